// Round 2
// baseline (442.223 us; speedup 1.0000x reference)
//
#include <hip/hip_runtime.h>
#include <cstddef>

typedef __bf16 bf16;
typedef __bf16 bf16x8 __attribute__((ext_vector_type(8)));
typedef short  s16x8  __attribute__((ext_vector_type(8)));
typedef float  f32x4  __attribute__((ext_vector_type(4)));

// ---------------------------------------------------------------------------
// MFMA wrapper robust to builtin operand type (__bf16 vector vs short vector)
// ---------------------------------------------------------------------------
template <class T> T&& declv() noexcept;
template <class, class = void> struct takes_bf16vec { static constexpr bool value = false; };
template <class V> struct takes_bf16vec<V, decltype((void)__builtin_amdgcn_mfma_f32_16x16x32_bf16(
    declv<V>(), declv<V>(), declv<f32x4>(), 0, 0, 0))> { static constexpr bool value = true; };

template <class V>
__device__ __forceinline__ f32x4 mfma_bf16_16x16x32(V a, V b, f32x4 c) {
  if constexpr (takes_bf16vec<V>::value) {
    return __builtin_amdgcn_mfma_f32_16x16x32_bf16(a, b, c, 0, 0, 0);
  } else {
    return __builtin_amdgcn_mfma_f32_16x16x32_bf16(
        __builtin_bit_cast(s16x8, a), __builtin_bit_cast(s16x8, b), c, 0, 0, 0);
  }
}

constexpr int M_NONE = 0, M_SILU = 1, M_SIG = 2;

// ---------------------------------------------------------------------------
// LayerNorm: x[64][1024] f32 -> xn bf16.  Also initializes
// out_final[b][j] = x[b][j] + b_down[j]  (base for the atomic W_down GEMM).
// ---------------------------------------------------------------------------
__global__ __launch_bounds__(256) void ln_kernel(const float* __restrict__ x,
                                                 const float* __restrict__ w,
                                                 const float* __restrict__ bs,
                                                 const float* __restrict__ bdown,
                                                 bf16* __restrict__ xn,
                                                 float* __restrict__ outf) {
  const int b = blockIdx.x, tid = threadIdx.x;
  __shared__ float red[256];
  float vals[4];
  float s = 0.f;
#pragma unroll
  for (int i = 0; i < 4; ++i) { vals[i] = x[b * 1024 + i * 256 + tid]; s += vals[i]; }
  red[tid] = s; __syncthreads();
  for (int off = 128; off; off >>= 1) { if (tid < off) red[tid] += red[tid + off]; __syncthreads(); }
  const float mu = red[0] * (1.f / 1024.f);
  __syncthreads();
  float s2 = 0.f;
#pragma unroll
  for (int i = 0; i < 4; ++i) { const float d = vals[i] - mu; s2 += d * d; }
  red[tid] = s2; __syncthreads();
  for (int off = 128; off; off >>= 1) { if (tid < off) red[tid] += red[tid + off]; __syncthreads(); }
  const float rs = rsqrtf(red[0] * (1.f / 1024.f) + 1e-5f);
#pragma unroll
  for (int i = 0; i < 4; ++i) {
    const int j = i * 256 + tid;
    xn[b * 1024 + j] = (bf16)((vals[i] - mu) * rs * w[j] + bs[j]);
    outf[b * 1024 + j] = vals[i] + bdown[j];   // final-residual base
  }
}

// ---------------------------------------------------------------------------
// One 64x16 output tile: NW waves split K, LDS-reduce, bias+activation epilogue.
// ---------------------------------------------------------------------------
template <int K, int NW>
__device__ __forceinline__ void gemm_tile(
    const bf16* __restrict__ A, int ldA, int aOff,
    const float* __restrict__ W, int ldB, int wcol,
    const float* __restrict__ bias, int bOff, float scale, int mode,
    float* __restrict__ outF, bf16* __restrict__ outB, int outLd, int oOff,
    float lds[NW][64][20]) {
  const int tid = threadIdx.x;
  const int lane = tid & 63, wave = tid >> 6;
  const int l15 = lane & 15, quad = lane >> 4;
  constexpr int chunk = K / NW;
  const int kbeg = wave * chunk;
  f32x4 acc0{}, acc1{}, acc2{}, acc3{};
#pragma unroll 4
  for (int k = 0; k < chunk; k += 32) {
    const int kk = kbeg + k + quad * 8;
    bf16x8 bfrag;
    const float* wp = W + (size_t)kk * ldB + wcol + l15;
#pragma unroll
    for (int j = 0; j < 8; ++j) bfrag[j] = (bf16)wp[(size_t)j * ldB];
    const bf16* ap = A + (size_t)l15 * ldA + aOff + kk;
    const size_t st = (size_t)16 * ldA;
    bf16x8 a0 = *(const bf16x8*)(ap);
    bf16x8 a1 = *(const bf16x8*)(ap + st);
    bf16x8 a2 = *(const bf16x8*)(ap + 2 * st);
    bf16x8 a3 = *(const bf16x8*)(ap + 3 * st);
    acc0 = mfma_bf16_16x16x32(a0, bfrag, acc0);
    acc1 = mfma_bf16_16x16x32(a1, bfrag, acc1);
    acc2 = mfma_bf16_16x16x32(a2, bfrag, acc2);
    acc3 = mfma_bf16_16x16x32(a3, bfrag, acc3);
  }
#pragma unroll
  for (int r = 0; r < 4; ++r) {
    const int rr = quad * 4 + r;  // C/D: row = quad*4+reg, col = lane&15
    lds[wave][rr][l15]      = acc0[r];
    lds[wave][16 + rr][l15] = acc1[r];
    lds[wave][32 + rr][l15] = acc2[r];
    lds[wave][48 + rr][l15] = acc3[r];
  }
  __syncthreads();
  if (tid < 256) {
    const int col = tid & 15, rb = (tid >> 4) << 2;
    const float bvv = bias[bOff + col];
#pragma unroll
    for (int r2 = 0; r2 < 4; ++r2) {
      const int row = rb + r2;
      float v = bvv;
#pragma unroll
      for (int w = 0; w < NW; ++w) v += lds[w][row][col];
      v *= scale;
      if (mode == M_SILU)      v = v / (1.f + expf(-v));
      else if (mode == M_SIG)  v = 1.f / (1.f + expf(-v));
      const size_t oi = (size_t)row * outLd + oOff + col;
      if (outF) outF[oi] = v;
      if (outB) outB[oi] = (bf16)v;
    }
  }
}

// ---------------------------------------------------------------------------
// ul+ur fused GEMM: 512-thread blocks (8-wave K-split), grid 256,
// XCD-chunked swizzle so adjacent 16-col tiles (sharing 128B weight lines)
// land on the same XCD's L2.
// ---------------------------------------------------------------------------
__global__ __launch_bounds__(512) void gemm_ulur(
    const bf16* __restrict__ xn,
    const float* __restrict__ W_ul, const float* __restrict__ W_ur,
    const float* __restrict__ b_ul, const float* __restrict__ b_ur,
    bf16* __restrict__ xl_bf, float* __restrict__ xr_f) {
  __shared__ float lds[8][64][20];
  const int l = (blockIdx.x & 7) * 32 + (blockIdx.x >> 3);  // 256 = 8*32
  const int ncol = (l & 127) * 16;
  if (l >> 7) {
    gemm_tile<1024, 8>(xn, 1024, 0, W_ur, 2048, ncol, b_ur, ncol, 1.f, M_NONE,
                       xr_f, nullptr, 2048, ncol, lds);
  } else {
    gemm_tile<1024, 8>(xn, 1024, 0, W_ul, 2048, ncol, b_ul, ncol, 1.f, M_NONE,
                       nullptr, xl_bf, 2048, ncol, lds);
  }
}

// ---------------------------------------------------------------------------
// conv tap-3 GEMM: 8-column tiles -> grid 256 (full GPU), 8 waves each.
// B cols duplicated across l15 8..15 (results discarded) — compute is free,
// the 67 MB strided tap fetch is the cost and now spreads over all CUs.
// ---------------------------------------------------------------------------
__global__ __launch_bounds__(512) void gemm_conv(
    const bf16* __restrict__ xl, const float* __restrict__ Wc,
    const float* __restrict__ bc, bf16* __restrict__ xc) {
  __shared__ float lds[8][64][20];
  const int tid = threadIdx.x;
  const int lane = tid & 63, wave = tid >> 6;
  const int l15 = lane & 15, quad = lane >> 4;
  const int n0 = blockIdx.x * 8;
  const int kbeg = wave * 256;
  f32x4 acc0{}, acc1{}, acc2{}, acc3{};
#pragma unroll 4
  for (int k = 0; k < 256; k += 32) {
    const int kk = kbeg + k + quad * 8;
    bf16x8 bfrag;
    const float* wp = Wc + ((size_t)(n0 + (l15 & 7)) * 2048 + kk) * 4 + 3;
#pragma unroll
    for (int j = 0; j < 8; ++j) bfrag[j] = (bf16)wp[j * 4];
    const bf16* ap = xl + (size_t)l15 * 2048 + kk;
    const size_t st = (size_t)16 * 2048;
    bf16x8 a0 = *(const bf16x8*)(ap);
    bf16x8 a1 = *(const bf16x8*)(ap + st);
    bf16x8 a2 = *(const bf16x8*)(ap + 2 * st);
    bf16x8 a3 = *(const bf16x8*)(ap + 3 * st);
    acc0 = mfma_bf16_16x16x32(a0, bfrag, acc0);
    acc1 = mfma_bf16_16x16x32(a1, bfrag, acc1);
    acc2 = mfma_bf16_16x16x32(a2, bfrag, acc2);
    acc3 = mfma_bf16_16x16x32(a3, bfrag, acc3);
  }
#pragma unroll
  for (int r = 0; r < 4; ++r) {
    const int rr = quad * 4 + r;
    lds[wave][rr][l15]      = acc0[r];
    lds[wave][16 + rr][l15] = acc1[r];
    lds[wave][32 + rr][l15] = acc2[r];
    lds[wave][48 + rr][l15] = acc3[r];
  }
  __syncthreads();
  if (tid < 128) {
    const int col = tid & 7, rb = (tid >> 3) << 2;
    const float bvv = bc[n0 + col];
#pragma unroll
    for (int r2 = 0; r2 < 4; ++r2) {
      const int row = rb + r2;
      float v = bvv;
#pragma unroll
      for (int w = 0; w < 8; ++w) v += lds[w][row][col];
      v = v / (1.f + expf(-v));   // silu
      xc[(size_t)row * 2048 + n0 + col] = (bf16)v;
    }
  }
}

// ---------------------------------------------------------------------------
// mega_c: everything that depends only on {xc, xl}, one launch (XCD-swizzled).
//   logical [0,256):   skip (A=xc) / o (A=xl, sigmoid)  fused dual GEMM
//   logical [256,640): block-diagonal q/k/v GEMMs (K=256 per head)
//   logical [640,704): i_t/f_t GEMV + stabilized gates + m_t
// ---------------------------------------------------------------------------
__global__ __launch_bounds__(256) void mega_c(
    const bf16* __restrict__ xc, const bf16* __restrict__ xl,
    const float* __restrict__ W_skip, const float* __restrict__ b_skip,
    const float* __restrict__ W_o, const float* __restrict__ b_o,
    const float* __restrict__ Wq, const float* __restrict__ bq,
    const float* __restrict__ Wk, const float* __restrict__ bk,
    const float* __restrict__ Wv, const float* __restrict__ bv,
    const float* __restrict__ Wi, const float* __restrict__ bi,
    const float* __restrict__ Wf, const float* __restrict__ bfv,
    const float* __restrict__ m_prev,
    float* __restrict__ xskip_f, float* __restrict__ o_f,
    float* __restrict__ qf, float* __restrict__ kf, float* __restrict__ vf,
    float* __restrict__ ig, float* __restrict__ fgo, float* __restrict__ mt_out) {
  __shared__ float lds[4][64][20];  // 20 KB; gates branch reuses first 16 KB
  const int bid = (blockIdx.x & 7) * 88 + (blockIdx.x >> 3);  // 704 = 8*88
  if (bid < 256) {
    const int seg = bid >> 7, ncol = (bid & 127) * 16;
    if (seg) {
      gemm_tile<2048, 4>(xl, 2048, 0, W_o, 2048, ncol, b_o, ncol, 1.f, M_SIG,
                         o_f, nullptr, 2048, ncol, lds);
    } else {
      gemm_tile<2048, 4>(xc, 2048, 0, W_skip, 2048, ncol, b_skip, ncol, 1.f, M_NONE,
                         xskip_f, nullptr, 2048, ncol, lds);
    }
  } else if (bid < 640) {
    const int t6 = bid - 256;
    const int seg = t6 >> 7, t = t6 & 127;
    const int n0 = t * 16, h = t >> 4;
    const bf16* A = (seg == 2) ? xl : xc;
    const float* W = (seg == 0) ? Wq : (seg == 1) ? Wk : Wv;
    const float* bias = (seg == 0) ? bq : (seg == 1) ? bk : bv;
    float* out = (seg == 0) ? qf : (seg == 1) ? kf : vf;
    gemm_tile<256, 4>(A, 2048, h << 8, W + (size_t)h * 65536, 256, n0 & 255,
                      bias, n0, (seg == 1) ? 0.0625f : 1.f, M_NONE,
                      out, nullptr, 2048, n0, lds);
  } else {
    // gates: i_t/f_t GEMV over xc, stabilized exponential gating
    const int b = bid - 640, tid = threadIdx.x;
    float* shf = &lds[0][0][0];
    float (*ri)[8] = reinterpret_cast<float(*)[8]>(shf);          // 256*8
    float (*rf)[8] = reinterpret_cast<float(*)[8]>(shf + 2048);   // 256*8
    float ai[8] = {}, af[8] = {};
    for (int k = tid; k < 2048; k += 256) {
      const float xv = (float)xc[b * 2048 + k];
      const float4 wi0 = *(const float4*)(Wi + (size_t)k * 8);
      const float4 wi1 = *(const float4*)(Wi + (size_t)k * 8 + 4);
      const float4 wf0 = *(const float4*)(Wf + (size_t)k * 8);
      const float4 wf1 = *(const float4*)(Wf + (size_t)k * 8 + 4);
      ai[0] += xv * wi0.x; ai[1] += xv * wi0.y; ai[2] += xv * wi0.z; ai[3] += xv * wi0.w;
      ai[4] += xv * wi1.x; ai[5] += xv * wi1.y; ai[6] += xv * wi1.z; ai[7] += xv * wi1.w;
      af[0] += xv * wf0.x; af[1] += xv * wf0.y; af[2] += xv * wf0.z; af[3] += xv * wf0.w;
      af[4] += xv * wf1.x; af[5] += xv * wf1.y; af[6] += xv * wf1.z; af[7] += xv * wf1.w;
    }
#pragma unroll
    for (int h = 0; h < 8; ++h) { ri[tid][h] = ai[h]; rf[tid][h] = af[h]; }
    __syncthreads();
    for (int off = 128; off; off >>= 1) {
      if (tid < off) {
#pragma unroll
        for (int h = 0; h < 8; ++h) { ri[tid][h] += ri[tid + off][h]; rf[tid][h] += rf[tid + off][h]; }
      }
      __syncthreads();
    }
    if (tid < 8) {
      const float it = ri[0][tid] + bi[tid];
      const float ft = rf[0][tid] + bfv[tid];
      const float mp = m_prev[b * 8 + tid];
      const float mt = fmaxf(ft + mp, it);
      mt_out[b * 8 + tid] = mt;
      ig[b * 8 + tid] = expf(it - mt);
      fgo[b * 8 + tid] = expf(ft + mp - mt);
    }
  }
}

// ---------------------------------------------------------------------------
// state_fused: one block per (b,h).
//   phase 1: c_t = f*c_prev + i*v⊗k, num[row] = c_t[row]·q   (num kept in LDS)
//   phase 2: n_t, den, h_t, GroupNorm, pre = (gn*w+b + skip)*silu(xr)
// ---------------------------------------------------------------------------
__global__ __launch_bounds__(256) void state_fused(
    const float* __restrict__ c_prev, const float* __restrict__ n_prev,
    const float* __restrict__ qf, const float* __restrict__ kf,
    const float* __restrict__ vf, const float* __restrict__ of,
    const float* __restrict__ ig, const float* __restrict__ fg,
    const float* __restrict__ xskip, const float* __restrict__ xrf,
    const float* __restrict__ gnw, const float* __restrict__ gnb,
    float* __restrict__ ct_out, float* __restrict__ nt_out,
    float* __restrict__ ht_out, bf16* __restrict__ pre_bf) {
  const int bh = blockIdx.x, b = bh >> 3, h = bh & 7;
  const int tid = threadIdx.x;
  const int vb = b * 2048 + h * 256;
  __shared__ float q_s[256], k_s[256], num_s[256], red[256];
  q_s[tid] = qf[vb + tid];
  k_s[tid] = kf[vb + tid];
  const float i_g = ig[bh], f_g = fg[bh];
  __syncthreads();
  const int lane8 = tid & 7, rowbase = tid >> 3;
#pragma unroll
  for (int rg = 0; rg < 8; ++rg) {
    const int row = rg * 32 + rowbase;
    const float iv = i_g * vf[vb + row];
    const size_t base = ((size_t)bh << 16) + ((size_t)row << 8) + lane8 * 4;
    float p = 0.f;
#pragma unroll
    for (int i = 0; i < 8; ++i) {
      const int c = lane8 * 4 + i * 32;
      const float4 cp = *(const float4*)(c_prev + base + i * 32);
      float4 cn;
      cn.x = f_g * cp.x + iv * k_s[c];
      cn.y = f_g * cp.y + iv * k_s[c + 1];
      cn.z = f_g * cp.z + iv * k_s[c + 2];
      cn.w = f_g * cp.w + iv * k_s[c + 3];
      *(float4*)(ct_out + base + i * 32) = cn;
      p += cn.x * q_s[c] + cn.y * q_s[c + 1] + cn.z * q_s[c + 2] + cn.w * q_s[c + 3];
    }
    p += __shfl_xor(p, 1, 64);
    p += __shfl_xor(p, 2, 64);
    p += __shfl_xor(p, 4, 64);
    if (lane8 == 0) num_s[row] = p;
  }
  __syncthreads();
  // phase 2, q/k from LDS, num from LDS
  const float qv = q_s[tid], kv = k_s[tid];
  const float nv = f_g * n_prev[bh * 256 + tid] + i_g * kv;
  nt_out[bh * 256 + tid] = nv;
  red[tid] = nv * qv;
  __syncthreads();
  for (int off = 128; off; off >>= 1) { if (tid < off) red[tid] += red[tid + off]; __syncthreads(); }
  const float den = fmaxf(red[0], 1.0f);
  const float hv = of[vb + tid] * num_s[tid] / den;
  ht_out[bh * 256 + tid] = hv;
  __syncthreads();
  red[tid] = hv; __syncthreads();
  for (int off = 128; off; off >>= 1) { if (tid < off) red[tid] += red[tid + off]; __syncthreads(); }
  const float mu = red[0] * (1.f / 256.f);
  __syncthreads();
  const float dv = hv - mu;
  red[tid] = dv * dv; __syncthreads();
  for (int off = 128; off; off >>= 1) { if (tid < off) red[tid] += red[tid + off]; __syncthreads(); }
  const float gn = (hv - mu) * rsqrtf(red[0] * (1.f / 256.f) + 1e-5f);
  const int j = h * 256 + tid;
  const float xr = xrf[b * 2048 + j];
  const float pre = (gn * gnw[j] + gnb[j] + xskip[b * 2048 + j]) * (xr / (1.f + expf(-xr)));
  pre_bf[b * 2048 + j] = (bf16)pre;
}

// ---------------------------------------------------------------------------
// Split-K atomic GEMM for W_down (base out_final = x + b_down from ln_kernel).
// XCD-swizzled: each XCD owns one full ks-slice -> adjacent tiles share L2.
// ---------------------------------------------------------------------------
template <int K, int KS, int NTILES>
__global__ __launch_bounds__(256) void gemm_atomic(
    const bf16* __restrict__ A, const float* __restrict__ W,
    int ldA, int ldB, float* __restrict__ dst, int outN) {
  constexpr int Kslice = K / KS;
  constexpr int chunk = Kslice / 4;
  const int tid = threadIdx.x;
  const int lane = tid & 63, wave = tid >> 6;
  const int l15 = lane & 15, quad = lane >> 4;
  const int l = (blockIdx.x & 7) * ((NTILES * KS) / 8) + (blockIdx.x >> 3);
  const int tile = l % NTILES, ks = l / NTILES;
  const int ncol = tile * 16;
  const int kbeg = ks * Kslice + wave * chunk;

  f32x4 acc0{}, acc1{}, acc2{}, acc3{};
#pragma unroll
  for (int k = 0; k < chunk; k += 32) {
    const int kk = kbeg + k + quad * 8;
    bf16x8 bfrag;
    const float* wp = W + (size_t)kk * ldB + ncol + l15;
#pragma unroll
    for (int j = 0; j < 8; ++j) bfrag[j] = (bf16)wp[(size_t)j * ldB];
    const bf16* ap = A + (size_t)l15 * ldA + kk;
    const size_t st = (size_t)16 * ldA;
    bf16x8 a0 = *(const bf16x8*)(ap);
    bf16x8 a1 = *(const bf16x8*)(ap + st);
    bf16x8 a2 = *(const bf16x8*)(ap + 2 * st);
    bf16x8 a3 = *(const bf16x8*)(ap + 3 * st);
    acc0 = mfma_bf16_16x16x32(a0, bfrag, acc0);
    acc1 = mfma_bf16_16x16x32(a1, bfrag, acc1);
    acc2 = mfma_bf16_16x16x32(a2, bfrag, acc2);
    acc3 = mfma_bf16_16x16x32(a3, bfrag, acc3);
  }
  __shared__ float lds[4][64][20];
#pragma unroll
  for (int r = 0; r < 4; ++r) {
    const int rr = quad * 4 + r;
    lds[wave][rr][l15]      = acc0[r];
    lds[wave][16 + rr][l15] = acc1[r];
    lds[wave][32 + rr][l15] = acc2[r];
    lds[wave][48 + rr][l15] = acc3[r];
  }
  __syncthreads();
  const int col = tid & 15, rb = (tid >> 4) << 2;
#pragma unroll
  for (int r2 = 0; r2 < 4; ++r2) {
    const int row = rb + r2;
    const float v = lds[0][row][col] + lds[1][row][col] + lds[2][row][col] + lds[3][row][col];
    atomicAdd(dst + (size_t)row * outN + ncol + col, v);
  }
}

// ---------------------------------------------------------------------------
extern "C" void kernel_launch(void* const* d_in, const int* in_sizes, int n_in,
                              void* d_out, int out_size, void* d_ws, size_t ws_size,
                              hipStream_t stream) {
  (void)in_sizes; (void)n_in; (void)out_size; (void)ws_size;
  const float* x      = (const float*)d_in[0];
  const float* c_prev = (const float*)d_in[2];
  const float* n_prev = (const float*)d_in[3];
  const float* m_prev = (const float*)d_in[4];
  const float* ln_w = (const float*)d_in[5];
  const float* ln_b = (const float*)d_in[6];
  const float* W_ul = (const float*)d_in[7];
  const float* b_ul = (const float*)d_in[8];
  const float* W_ur = (const float*)d_in[9];
  const float* b_ur = (const float*)d_in[10];
  const float* W_conv = (const float*)d_in[11];
  const float* b_conv = (const float*)d_in[12];
  const float* W_skip = (const float*)d_in[13];
  const float* b_skip = (const float*)d_in[14];
  const float* W_q = (const float*)d_in[15];
  const float* b_q = (const float*)d_in[16];
  const float* W_k = (const float*)d_in[17];
  const float* b_k = (const float*)d_in[18];
  const float* W_v = (const float*)d_in[19];
  const float* b_v = (const float*)d_in[20];
  const float* W_i = (const float*)d_in[21];
  const float* b_i = (const float*)d_in[22];
  const float* W_f = (const float*)d_in[23];
  const float* b_f = (const float*)d_in[24];
  const float* W_o = (const float*)d_in[25];
  const float* b_o = (const float*)d_in[26];
  const float* W_down = (const float*)d_in[27];
  const float* b_down = (const float*)d_in[28];
  const float* gn_w = (const float*)d_in[29];
  const float* gn_b = (const float*)d_in[30];

  // d_out layout (f32 elements): final | h_t | c_t | n_t | m_t
  float* out_final = (float*)d_out;
  float* out_ht = out_final + 65536;
  float* out_ct = out_final + 196608;
  float* out_nt = out_final + 33751040;
  float* out_mt = out_final + 33882112;

  char* ws = (char*)d_ws;
  bf16*  xn_bf   = (bf16*)(ws + 0);         // 128 KB
  bf16*  xl_bf   = (bf16*)(ws + 131072);    // 256 KB
  bf16*  xc_bf   = (bf16*)(ws + 393216);    // 256 KB
  bf16*  pre_bf  = (bf16*)(ws + 655360);    // 256 KB
  float* xr_f    = (float*)(ws + 917504);   // 512 KB
  float* xskip_f = (float*)(ws + 1441792);  // 512 KB
  float* q_f     = (float*)(ws + 1966080);
  float* k_f     = (float*)(ws + 2490368);
  float* v_f     = (float*)(ws + 3014656);
  float* o_f     = (float*)(ws + 3538944);
  float* ig_f    = (float*)(ws + 4063232);  // 2 KB
  float* fg_f    = (float*)(ws + 4065280);  // 2 KB

  // 1. LayerNorm + final-residual base
  ln_kernel<<<64, 256, 0, stream>>>(x, ln_w, ln_b, b_down, xn_bf, out_final);
  // 2. ul+ur fused GEMM (K=1024, N=2048+2048), 8-wave blocks, XCD-swizzled
  gemm_ulur<<<256, 512, 0, stream>>>(xn_bf, W_ul, W_ur, b_ul, b_ur, xl_bf, xr_f);
  // 3. conv tap-3 GEMM, 8-col tiles -> full-GPU grid, direct strided read
  gemm_conv<<<256, 512, 0, stream>>>(xl_bf, W_conv, b_conv, xc_bf);
  // 4. skip + o + q/k/v + gates, one launch (XCD-swizzled)
  mega_c<<<704, 256, 0, stream>>>(
      xc_bf, xl_bf, W_skip, b_skip, W_o, b_o, W_q, b_q, W_k, b_k, W_v, b_v,
      W_i, b_i, W_f, b_f, m_prev, xskip_f, o_f, q_f, k_f, v_f, ig_f, fg_f, out_mt);
  // 5. fused state update + readout + GroupNorm + pre-down activation
  state_fused<<<512, 256, 0, stream>>>(
      c_prev, n_prev, q_f, k_f, v_f, o_f, ig_f, fg_f,
      xskip_f, xr_f, gn_w, gn_b, out_ct, out_nt, out_ht, pre_bf);
  // 6. W_down: split-K atomic into out_final (base = x + b_down)
  gemm_atomic<2048, 8, 64><<<512, 256, 0, stream>>>(
      pre_bf, W_down, 2048, 1024, out_final, 1024);
}

// Round 3
// 424.931 us; speedup vs baseline: 1.0407x; 1.0407x over previous
//
#include <hip/hip_runtime.h>
#include <cstddef>

typedef __bf16 bf16;
typedef __bf16 bf16x8 __attribute__((ext_vector_type(8)));
typedef short  s16x8  __attribute__((ext_vector_type(8)));
typedef float  f32x4  __attribute__((ext_vector_type(4)));

// ---------------------------------------------------------------------------
// MFMA wrapper robust to builtin operand type (__bf16 vector vs short vector)
// ---------------------------------------------------------------------------
template <class T> T&& declv() noexcept;
template <class, class = void> struct takes_bf16vec { static constexpr bool value = false; };
template <class V> struct takes_bf16vec<V, decltype((void)__builtin_amdgcn_mfma_f32_16x16x32_bf16(
    declv<V>(), declv<V>(), declv<f32x4>(), 0, 0, 0))> { static constexpr bool value = true; };

template <class V>
__device__ __forceinline__ f32x4 mfma_bf16_16x16x32(V a, V b, f32x4 c) {
  if constexpr (takes_bf16vec<V>::value) {
    return __builtin_amdgcn_mfma_f32_16x16x32_bf16(a, b, c, 0, 0, 0);
  } else {
    return __builtin_amdgcn_mfma_f32_16x16x32_bf16(
        __builtin_bit_cast(s16x8, a), __builtin_bit_cast(s16x8, b), c, 0, 0, 0);
  }
}

constexpr int M_NONE = 0, M_SILU = 1, M_SIG = 2;

// ---------------------------------------------------------------------------
// LayerNorm: x[64][1024] f32 -> xn bf16.  Also initializes
// out_final[b][j] = x[b][j] + b_down[j]  (base for the atomic W_down GEMM).
// ---------------------------------------------------------------------------
__global__ __launch_bounds__(256) void ln_kernel(const float* __restrict__ x,
                                                 const float* __restrict__ w,
                                                 const float* __restrict__ bs,
                                                 const float* __restrict__ bdown,
                                                 bf16* __restrict__ xn,
                                                 float* __restrict__ outf) {
  const int b = blockIdx.x, tid = threadIdx.x;
  __shared__ float red[256];
  float vals[4];
  float s = 0.f;
#pragma unroll
  for (int i = 0; i < 4; ++i) { vals[i] = x[b * 1024 + i * 256 + tid]; s += vals[i]; }
  red[tid] = s; __syncthreads();
  for (int off = 128; off; off >>= 1) { if (tid < off) red[tid] += red[tid + off]; __syncthreads(); }
  const float mu = red[0] * (1.f / 1024.f);
  __syncthreads();
  float s2 = 0.f;
#pragma unroll
  for (int i = 0; i < 4; ++i) { const float d = vals[i] - mu; s2 += d * d; }
  red[tid] = s2; __syncthreads();
  for (int off = 128; off; off >>= 1) { if (tid < off) red[tid] += red[tid + off]; __syncthreads(); }
  const float rs = rsqrtf(red[0] * (1.f / 1024.f) + 1e-5f);
#pragma unroll
  for (int i = 0; i < 4; ++i) {
    const int j = i * 256 + tid;
    xn[b * 1024 + j] = (bf16)((vals[i] - mu) * rs * w[j] + bs[j]);
    outf[b * 1024 + j] = vals[i] + bdown[j];   // final-residual base
  }
}

// ---------------------------------------------------------------------------
// One 64x16 output tile: 4 waves split K, LDS-reduce, bias+activation epilogue.
// TAP: B element = W[(wcol+n)*K*4 + k*4 + 3]  (conv tap-3 read, no repack).
// ---------------------------------------------------------------------------
template <int K, bool TAP>
__device__ __forceinline__ void gemm_tile(
    const bf16* __restrict__ A, int ldA, int aOff,
    const float* __restrict__ W, int ldB, int wcol,
    const float* __restrict__ bias, int bOff, float scale, int mode,
    float* __restrict__ outF, bf16* __restrict__ outB, int outLd, int oOff,
    float lds[4][64][20]) {
  const int tid = threadIdx.x;
  const int lane = tid & 63, wave = tid >> 6;
  const int l15 = lane & 15, quad = lane >> 4;
  constexpr int chunk = K / 4;
  const int kbeg = wave * chunk;
  f32x4 acc0{}, acc1{}, acc2{}, acc3{};
#pragma unroll 4
  for (int k = 0; k < chunk; k += 32) {
    const int kk = kbeg + k + quad * 8;
    bf16x8 bfrag;
    if (TAP) {
      const float* wp = W + ((size_t)(wcol + l15) * K + kk) * 4 + 3;
#pragma unroll
      for (int j = 0; j < 8; ++j) bfrag[j] = (bf16)wp[j * 4];
    } else {
      const float* wp = W + (size_t)kk * ldB + wcol + l15;
#pragma unroll
      for (int j = 0; j < 8; ++j) bfrag[j] = (bf16)wp[(size_t)j * ldB];
    }
    const bf16* ap = A + (size_t)l15 * ldA + aOff + kk;
    const size_t st = (size_t)16 * ldA;
    bf16x8 a0 = *(const bf16x8*)(ap);
    bf16x8 a1 = *(const bf16x8*)(ap + st);
    bf16x8 a2 = *(const bf16x8*)(ap + 2 * st);
    bf16x8 a3 = *(const bf16x8*)(ap + 3 * st);
    acc0 = mfma_bf16_16x16x32(a0, bfrag, acc0);
    acc1 = mfma_bf16_16x16x32(a1, bfrag, acc1);
    acc2 = mfma_bf16_16x16x32(a2, bfrag, acc2);
    acc3 = mfma_bf16_16x16x32(a3, bfrag, acc3);
  }
#pragma unroll
  for (int r = 0; r < 4; ++r) {
    const int rr = quad * 4 + r;  // C/D: row = quad*4+reg, col = lane&15
    lds[wave][rr][l15]      = acc0[r];
    lds[wave][16 + rr][l15] = acc1[r];
    lds[wave][32 + rr][l15] = acc2[r];
    lds[wave][48 + rr][l15] = acc3[r];
  }
  __syncthreads();
  const int col = tid & 15, rb = (tid >> 4) << 2;
  const float bvv = bias[bOff + col];
#pragma unroll
  for (int r2 = 0; r2 < 4; ++r2) {
    const int row = rb + r2;
    float v = (lds[0][row][col] + lds[1][row][col] + lds[2][row][col] + lds[3][row][col] + bvv) * scale;
    if (mode == M_SILU)      v = v / (1.f + expf(-v));
    else if (mode == M_SIG)  v = 1.f / (1.f + expf(-v));
    const size_t oi = (size_t)row * outLd + oOff + col;
    if (outF) outF[oi] = v;
    if (outB) outB[oi] = (bf16)v;
  }
}

// ---------------------------------------------------------------------------
// Single-launch GEMM (no split-K, no combine). DUAL = two A/W segments of
// 128 tiles each (fused independent GEMMs sharing one launch).
// ---------------------------------------------------------------------------
template <int K, bool TAP, bool DUAL>
__global__ __launch_bounds__(256) void gemm_full(
    const bf16* __restrict__ A0, const bf16* __restrict__ A1,
    const float* __restrict__ W0, const float* __restrict__ W1,
    int ldA, int ldB,
    const float* __restrict__ bias0, const float* __restrict__ bias1,
    int mode0, int mode1,
    float* __restrict__ outF0, bf16* __restrict__ outB0,
    float* __restrict__ outF1, bf16* __restrict__ outB1, int outLd) {
  __shared__ float lds[4][64][20];
  const int tile = blockIdx.x;
  if (DUAL) {
    const int ncol = (tile & 127) * 16;
    if (tile >> 7) {
      gemm_tile<K, TAP>(A1, ldA, 0, W1, ldB, ncol, bias1, ncol, 1.f, mode1,
                        outF1, outB1, outLd, ncol, lds);
    } else {
      gemm_tile<K, TAP>(A0, ldA, 0, W0, ldB, ncol, bias0, ncol, 1.f, mode0,
                        outF0, outB0, outLd, ncol, lds);
    }
  } else {
    const int ncol = tile * 16;
    gemm_tile<K, TAP>(A0, ldA, 0, W0, ldB, ncol, bias0, ncol, 1.f, mode0,
                      outF0, outB0, outLd, ncol, lds);
  }
}

// ---------------------------------------------------------------------------
// mega_c: everything that depends only on {xc, xl}, one launch.
//   blocks [0,256):   skip (A=xc) / o (A=xl, sigmoid)  fused dual GEMM
//   blocks [256,640): block-diagonal q/k/v GEMMs (K=256 per head)
//   blocks [640,704): i_t/f_t GEMV + stabilized gates + m_t
// ---------------------------------------------------------------------------
__global__ __launch_bounds__(256) void mega_c(
    const bf16* __restrict__ xc, const bf16* __restrict__ xl,
    const float* __restrict__ W_skip, const float* __restrict__ b_skip,
    const float* __restrict__ W_o, const float* __restrict__ b_o,
    const float* __restrict__ Wq, const float* __restrict__ bq,
    const float* __restrict__ Wk, const float* __restrict__ bk,
    const float* __restrict__ Wv, const float* __restrict__ bv,
    const float* __restrict__ Wi, const float* __restrict__ bi,
    const float* __restrict__ Wf, const float* __restrict__ bfv,
    const float* __restrict__ m_prev,
    float* __restrict__ xskip_f, float* __restrict__ o_f,
    float* __restrict__ qf, float* __restrict__ kf, float* __restrict__ vf,
    float* __restrict__ ig, float* __restrict__ fgo, float* __restrict__ mt_out) {
  __shared__ float lds[4][64][20];  // 20 KB; gates branch reuses first 16 KB
  const int bid = blockIdx.x;
  if (bid < 256) {
    const int seg = bid >> 7, ncol = (bid & 127) * 16;
    if (seg) {
      gemm_tile<2048, false>(xl, 2048, 0, W_o, 2048, ncol, b_o, ncol, 1.f, M_SIG,
                             o_f, nullptr, 2048, ncol, lds);
    } else {
      gemm_tile<2048, false>(xc, 2048, 0, W_skip, 2048, ncol, b_skip, ncol, 1.f, M_NONE,
                             xskip_f, nullptr, 2048, ncol, lds);
    }
  } else if (bid < 640) {
    const int t6 = bid - 256;
    const int seg = t6 >> 7, t = t6 & 127;
    const int n0 = t * 16, h = t >> 4;
    const bf16* A = (seg == 2) ? xl : xc;
    const float* W = (seg == 0) ? Wq : (seg == 1) ? Wk : Wv;
    const float* bias = (seg == 0) ? bq : (seg == 1) ? bk : bv;
    float* out = (seg == 0) ? qf : (seg == 1) ? kf : vf;
    gemm_tile<256, false>(A, 2048, h << 8, W + (size_t)h * 65536, 256, n0 & 255,
                          bias, n0, (seg == 1) ? 0.0625f : 1.f, M_NONE,
                          out, nullptr, 2048, n0, lds);
  } else {
    // gates: i_t/f_t GEMV over xc, stabilized exponential gating
    const int b = bid - 640, tid = threadIdx.x;
    float* shf = &lds[0][0][0];
    float (*ri)[8] = reinterpret_cast<float(*)[8]>(shf);          // 256*8
    float (*rf)[8] = reinterpret_cast<float(*)[8]>(shf + 2048);   // 256*8
    float ai[8] = {}, af[8] = {};
    for (int k = tid; k < 2048; k += 256) {
      const float xv = (float)xc[b * 2048 + k];
      const float4 wi0 = *(const float4*)(Wi + (size_t)k * 8);
      const float4 wi1 = *(const float4*)(Wi + (size_t)k * 8 + 4);
      const float4 wf0 = *(const float4*)(Wf + (size_t)k * 8);
      const float4 wf1 = *(const float4*)(Wf + (size_t)k * 8 + 4);
      ai[0] += xv * wi0.x; ai[1] += xv * wi0.y; ai[2] += xv * wi0.z; ai[3] += xv * wi0.w;
      ai[4] += xv * wi1.x; ai[5] += xv * wi1.y; ai[6] += xv * wi1.z; ai[7] += xv * wi1.w;
      af[0] += xv * wf0.x; af[1] += xv * wf0.y; af[2] += xv * wf0.z; af[3] += xv * wf0.w;
      af[4] += xv * wf1.x; af[5] += xv * wf1.y; af[6] += xv * wf1.z; af[7] += xv * wf1.w;
    }
#pragma unroll
    for (int h = 0; h < 8; ++h) { ri[tid][h] = ai[h]; rf[tid][h] = af[h]; }
    __syncthreads();
    for (int off = 128; off; off >>= 1) {
      if (tid < off) {
#pragma unroll
        for (int h = 0; h < 8; ++h) { ri[tid][h] += ri[tid + off][h]; rf[tid][h] += rf[tid + off][h]; }
      }
      __syncthreads();
    }
    if (tid < 8) {
      const float it = ri[0][tid] + bi[tid];
      const float ft = rf[0][tid] + bfv[tid];
      const float mp = m_prev[b * 8 + tid];
      const float mt = fmaxf(ft + mp, it);
      mt_out[b * 8 + tid] = mt;
      ig[b * 8 + tid] = expf(it - mt);
      fgo[b * 8 + tid] = expf(ft + mp - mt);
    }
  }
}

// ---------------------------------------------------------------------------
// state_fused: one block per (b,h).
//   phase 1: c_t = f*c_prev + i*v⊗k, num[row] = c_t[row]·q   (num kept in LDS)
//   phase 2: n_t, den, h_t, GroupNorm, pre = (gn*w+b + skip)*silu(xr)
// ---------------------------------------------------------------------------
__global__ __launch_bounds__(256) void state_fused(
    const float* __restrict__ c_prev, const float* __restrict__ n_prev,
    const float* __restrict__ qf, const float* __restrict__ kf,
    const float* __restrict__ vf, const float* __restrict__ of,
    const float* __restrict__ ig, const float* __restrict__ fg,
    const float* __restrict__ xskip, const float* __restrict__ xrf,
    const float* __restrict__ gnw, const float* __restrict__ gnb,
    float* __restrict__ ct_out, float* __restrict__ nt_out,
    float* __restrict__ ht_out, bf16* __restrict__ pre_bf) {
  const int bh = blockIdx.x, b = bh >> 3, h = bh & 7;
  const int tid = threadIdx.x;
  const int vb = b * 2048 + h * 256;
  __shared__ float q_s[256], k_s[256], num_s[256], red[256];
  q_s[tid] = qf[vb + tid];
  k_s[tid] = kf[vb + tid];
  const float i_g = ig[bh], f_g = fg[bh];
  __syncthreads();
  const int lane8 = tid & 7, rowbase = tid >> 3;
#pragma unroll
  for (int rg = 0; rg < 8; ++rg) {
    const int row = rg * 32 + rowbase;
    const float iv = i_g * vf[vb + row];
    const size_t base = ((size_t)bh << 16) + ((size_t)row << 8) + lane8 * 4;
    float p = 0.f;
#pragma unroll
    for (int i = 0; i < 8; ++i) {
      const int c = lane8 * 4 + i * 32;
      const float4 cp = *(const float4*)(c_prev + base + i * 32);
      float4 cn;
      cn.x = f_g * cp.x + iv * k_s[c];
      cn.y = f_g * cp.y + iv * k_s[c + 1];
      cn.z = f_g * cp.z + iv * k_s[c + 2];
      cn.w = f_g * cp.w + iv * k_s[c + 3];
      *(float4*)(ct_out + base + i * 32) = cn;
      p += cn.x * q_s[c] + cn.y * q_s[c + 1] + cn.z * q_s[c + 2] + cn.w * q_s[c + 3];
    }
    p += __shfl_xor(p, 1, 64);
    p += __shfl_xor(p, 2, 64);
    p += __shfl_xor(p, 4, 64);
    if (lane8 == 0) num_s[row] = p;
  }
  __syncthreads();
  // phase 2 (former state2), q/k from LDS, num from LDS
  const float qv = q_s[tid], kv = k_s[tid];
  const float nv = f_g * n_prev[bh * 256 + tid] + i_g * kv;
  nt_out[bh * 256 + tid] = nv;
  red[tid] = nv * qv;
  __syncthreads();
  for (int off = 128; off; off >>= 1) { if (tid < off) red[tid] += red[tid + off]; __syncthreads(); }
  const float den = fmaxf(red[0], 1.0f);
  const float hv = of[vb + tid] * num_s[tid] / den;
  ht_out[bh * 256 + tid] = hv;
  __syncthreads();
  red[tid] = hv; __syncthreads();
  for (int off = 128; off; off >>= 1) { if (tid < off) red[tid] += red[tid + off]; __syncthreads(); }
  const float mu = red[0] * (1.f / 256.f);
  __syncthreads();
  const float dv = hv - mu;
  red[tid] = dv * dv; __syncthreads();
  for (int off = 128; off; off >>= 1) { if (tid < off) red[tid] += red[tid + off]; __syncthreads(); }
  const float gn = (hv - mu) * rsqrtf(red[0] * (1.f / 256.f) + 1e-5f);
  const int j = h * 256 + tid;
  const float xr = xrf[b * 2048 + j];
  const float pre = (gn * gnw[j] + gnb[j] + xskip[b * 2048 + j]) * (xr / (1.f + expf(-xr)));
  pre_bf[b * 2048 + j] = (bf16)pre;
}

// ---------------------------------------------------------------------------
// Split-K atomic GEMM for W_down (base out_final = x + b_down from ln_kernel).
// ---------------------------------------------------------------------------
template <int K, int KS, int NTILES>
__global__ __launch_bounds__(256) void gemm_atomic(
    const bf16* __restrict__ A, const float* __restrict__ W,
    int ldA, int ldB, float* __restrict__ dst, int outN) {
  constexpr int Kslice = K / KS;
  constexpr int chunk = Kslice / 4;
  const int tid = threadIdx.x;
  const int lane = tid & 63, wave = tid >> 6;
  const int l15 = lane & 15, quad = lane >> 4;
  const int tile = blockIdx.x % NTILES, ks = blockIdx.x / NTILES;
  const int ncol = tile * 16;
  const int kbeg = ks * Kslice + wave * chunk;

  f32x4 acc0{}, acc1{}, acc2{}, acc3{};
#pragma unroll
  for (int k = 0; k < chunk; k += 32) {
    const int kk = kbeg + k + quad * 8;
    bf16x8 bfrag;
    const float* wp = W + (size_t)kk * ldB + ncol + l15;
#pragma unroll
    for (int j = 0; j < 8; ++j) bfrag[j] = (bf16)wp[(size_t)j * ldB];
    const bf16* ap = A + (size_t)l15 * ldA + kk;
    const size_t st = (size_t)16 * ldA;
    bf16x8 a0 = *(const bf16x8*)(ap);
    bf16x8 a1 = *(const bf16x8*)(ap + st);
    bf16x8 a2 = *(const bf16x8*)(ap + 2 * st);
    bf16x8 a3 = *(const bf16x8*)(ap + 3 * st);
    acc0 = mfma_bf16_16x16x32(a0, bfrag, acc0);
    acc1 = mfma_bf16_16x16x32(a1, bfrag, acc1);
    acc2 = mfma_bf16_16x16x32(a2, bfrag, acc2);
    acc3 = mfma_bf16_16x16x32(a3, bfrag, acc3);
  }
  __shared__ float lds[4][64][20];
#pragma unroll
  for (int r = 0; r < 4; ++r) {
    const int rr = quad * 4 + r;
    lds[wave][rr][l15]      = acc0[r];
    lds[wave][16 + rr][l15] = acc1[r];
    lds[wave][32 + rr][l15] = acc2[r];
    lds[wave][48 + rr][l15] = acc3[r];
  }
  __syncthreads();
  const int col = tid & 15, rb = (tid >> 4) << 2;
#pragma unroll
  for (int r2 = 0; r2 < 4; ++r2) {
    const int row = rb + r2;
    const float v = lds[0][row][col] + lds[1][row][col] + lds[2][row][col] + lds[3][row][col];
    atomicAdd(dst + (size_t)row * outN + ncol + col, v);
  }
}

// ---------------------------------------------------------------------------
extern "C" void kernel_launch(void* const* d_in, const int* in_sizes, int n_in,
                              void* d_out, int out_size, void* d_ws, size_t ws_size,
                              hipStream_t stream) {
  (void)in_sizes; (void)n_in; (void)out_size; (void)ws_size;
  const float* x      = (const float*)d_in[0];
  const float* c_prev = (const float*)d_in[2];
  const float* n_prev = (const float*)d_in[3];
  const float* m_prev = (const float*)d_in[4];
  const float* ln_w = (const float*)d_in[5];
  const float* ln_b = (const float*)d_in[6];
  const float* W_ul = (const float*)d_in[7];
  const float* b_ul = (const float*)d_in[8];
  const float* W_ur = (const float*)d_in[9];
  const float* b_ur = (const float*)d_in[10];
  const float* W_conv = (const float*)d_in[11];
  const float* b_conv = (const float*)d_in[12];
  const float* W_skip = (const float*)d_in[13];
  const float* b_skip = (const float*)d_in[14];
  const float* W_q = (const float*)d_in[15];
  const float* b_q = (const float*)d_in[16];
  const float* W_k = (const float*)d_in[17];
  const float* b_k = (const float*)d_in[18];
  const float* W_v = (const float*)d_in[19];
  const float* b_v = (const float*)d_in[20];
  const float* W_i = (const float*)d_in[21];
  const float* b_i = (const float*)d_in[22];
  const float* W_f = (const float*)d_in[23];
  const float* b_f = (const float*)d_in[24];
  const float* W_o = (const float*)d_in[25];
  const float* b_o = (const float*)d_in[26];
  const float* W_down = (const float*)d_in[27];
  const float* b_down = (const float*)d_in[28];
  const float* gn_w = (const float*)d_in[29];
  const float* gn_b = (const float*)d_in[30];

  // d_out layout (f32 elements): final | h_t | c_t | n_t | m_t
  float* out_final = (float*)d_out;
  float* out_ht = out_final + 65536;
  float* out_ct = out_final + 196608;
  float* out_nt = out_final + 33751040;
  float* out_mt = out_final + 33882112;

  char* ws = (char*)d_ws;
  bf16*  xn_bf   = (bf16*)(ws + 0);         // 128 KB
  bf16*  xl_bf   = (bf16*)(ws + 131072);    // 256 KB
  bf16*  xc_bf   = (bf16*)(ws + 393216);    // 256 KB
  bf16*  pre_bf  = (bf16*)(ws + 655360);    // 256 KB
  float* xr_f    = (float*)(ws + 917504);   // 512 KB
  float* xskip_f = (float*)(ws + 1441792);  // 512 KB
  float* q_f     = (float*)(ws + 1966080);
  float* k_f     = (float*)(ws + 2490368);
  float* v_f     = (float*)(ws + 3014656);
  float* o_f     = (float*)(ws + 3538944);
  float* ig_f    = (float*)(ws + 4063232);  // 2 KB
  float* fg_f    = (float*)(ws + 4065280);  // 2 KB

  // 1. LayerNorm + final-residual base
  ln_kernel<<<64, 256, 0, stream>>>(x, ln_w, ln_b, b_down, xn_bf, out_final);
  // 2. ul+ur fused single-launch GEMM (K=1024, N=2048+2048)
  gemm_full<1024, false, true><<<256, 256, 0, stream>>>(
      xn_bf, xn_bf, W_ul, W_ur, 1024, 2048,
      b_ul, b_ur, M_NONE, M_NONE, nullptr, xl_bf, xr_f, nullptr, 2048);
  // 3. conv tap-3 GEMM, direct strided read of W_conv (no repack), silu
  gemm_full<2048, true, false><<<128, 256, 0, stream>>>(
      xl_bf, nullptr, W_conv, nullptr, 2048, 0,
      b_conv, nullptr, M_SILU, M_NONE, nullptr, xc_bf, nullptr, nullptr, 2048);
  // 4. skip + o + q/k/v + gates, one launch
  mega_c<<<704, 256, 0, stream>>>(
      xc_bf, xl_bf, W_skip, b_skip, W_o, b_o, W_q, b_q, W_k, b_k, W_v, b_v,
      W_i, b_i, W_f, b_f, m_prev, xskip_f, o_f, q_f, k_f, v_f, ig_f, fg_f, out_mt);
  // 5. fused state update + readout + GroupNorm + pre-down activation
  state_fused<<<512, 256, 0, stream>>>(
      c_prev, n_prev, q_f, k_f, v_f, o_f, ig_f, fg_f,
      xskip_f, xr_f, gn_w, gn_b, out_ct, out_nt, out_ht, pre_bf);
  // 6. W_down: split-K atomic into out_final (base = x + b_down)
  gemm_atomic<2048, 8, 64><<<512, 256, 0, stream>>>(
      pre_bf, W_down, 2048, 1024, out_final, 1024);
}

// Round 5
// 423.068 us; speedup vs baseline: 1.0453x; 1.0044x over previous
//
#include <hip/hip_runtime.h>
#include <cstddef>

typedef __bf16 bf16;
typedef __bf16 bf16x8 __attribute__((ext_vector_type(8)));
typedef short  s16x8  __attribute__((ext_vector_type(8)));
typedef float  f32x4  __attribute__((ext_vector_type(4)));

// ---------------------------------------------------------------------------
// MFMA wrapper robust to builtin operand type (__bf16 vector vs short vector)
// ---------------------------------------------------------------------------
template <class T> T&& declv() noexcept;
template <class, class = void> struct takes_bf16vec { static constexpr bool value = false; };
template <class V> struct takes_bf16vec<V, decltype((void)__builtin_amdgcn_mfma_f32_16x16x32_bf16(
    declv<V>(), declv<V>(), declv<f32x4>(), 0, 0, 0))> { static constexpr bool value = true; };

template <class V>
__device__ __forceinline__ f32x4 mfma_bf16_16x16x32(V a, V b, f32x4 c) {
  if constexpr (takes_bf16vec<V>::value) {
    return __builtin_amdgcn_mfma_f32_16x16x32_bf16(a, b, c, 0, 0, 0);
  } else {
    return __builtin_amdgcn_mfma_f32_16x16x32_bf16(
        __builtin_bit_cast(s16x8, a), __builtin_bit_cast(s16x8, b), c, 0, 0, 0);
  }
}

constexpr int M_NONE = 0, M_SILU = 1, M_SIG = 2;

// Nontemporal 16B access via clang ext_vector type (float4/HIP_vector_type is
// rejected by __builtin_nontemporal_*).
__device__ __forceinline__ float4 nt_load4(const float* p) {
  f32x4 v = __builtin_nontemporal_load((const f32x4*)p);
  return *(float4*)&v;
}
__device__ __forceinline__ void nt_store4(float* p, float4 v) {
  __builtin_nontemporal_store(*(f32x4*)&v, (f32x4*)p);
}

// ---------------------------------------------------------------------------
// LayerNorm: x[64][1024] f32 -> xn bf16.  Also initializes
// out_final[b][j] = x[b][j] + b_down[j]  (base for the atomic W_down GEMM).
// ---------------------------------------------------------------------------
__global__ __launch_bounds__(256) void ln_kernel(const float* __restrict__ x,
                                                 const float* __restrict__ w,
                                                 const float* __restrict__ bs,
                                                 const float* __restrict__ bdown,
                                                 bf16* __restrict__ xn,
                                                 float* __restrict__ outf) {
  const int b = blockIdx.x, tid = threadIdx.x;
  __shared__ float red[256];
  float vals[4];
  float s = 0.f;
#pragma unroll
  for (int i = 0; i < 4; ++i) { vals[i] = x[b * 1024 + i * 256 + tid]; s += vals[i]; }
  red[tid] = s; __syncthreads();
  for (int off = 128; off; off >>= 1) { if (tid < off) red[tid] += red[tid + off]; __syncthreads(); }
  const float mu = red[0] * (1.f / 1024.f);
  __syncthreads();
  float s2 = 0.f;
#pragma unroll
  for (int i = 0; i < 4; ++i) { const float d = vals[i] - mu; s2 += d * d; }
  red[tid] = s2; __syncthreads();
  for (int off = 128; off; off >>= 1) { if (tid < off) red[tid] += red[tid + off]; __syncthreads(); }
  const float rs = rsqrtf(red[0] * (1.f / 1024.f) + 1e-5f);
#pragma unroll
  for (int i = 0; i < 4; ++i) {
    const int j = i * 256 + tid;
    xn[b * 1024 + j] = (bf16)((vals[i] - mu) * rs * w[j] + bs[j]);
    outf[b * 1024 + j] = vals[i] + bdown[j];   // final-residual base
  }
}

// ---------------------------------------------------------------------------
// One 64x16 output tile: 4 waves split K, LDS-reduce, bias+activation epilogue.
// ---------------------------------------------------------------------------
template <int K>
__device__ __forceinline__ void gemm_tile(
    const bf16* __restrict__ A, int ldA, int aOff,
    const float* __restrict__ W, int ldB, int wcol,
    const float* __restrict__ bias, int bOff, float scale, int mode,
    float* __restrict__ outF, bf16* __restrict__ outB, int outLd, int oOff,
    float lds[4][64][20]) {
  const int tid = threadIdx.x;
  const int lane = tid & 63, wave = tid >> 6;
  const int l15 = lane & 15, quad = lane >> 4;
  constexpr int chunk = K / 4;
  const int kbeg = wave * chunk;
  f32x4 acc0{}, acc1{}, acc2{}, acc3{};
#pragma unroll 4
  for (int k = 0; k < chunk; k += 32) {
    const int kk = kbeg + k + quad * 8;
    bf16x8 bfrag;
    const float* wp = W + (size_t)kk * ldB + wcol + l15;
#pragma unroll
    for (int j = 0; j < 8; ++j) bfrag[j] = (bf16)wp[(size_t)j * ldB];
    const bf16* ap = A + (size_t)l15 * ldA + aOff + kk;
    const size_t st = (size_t)16 * ldA;
    bf16x8 a0 = *(const bf16x8*)(ap);
    bf16x8 a1 = *(const bf16x8*)(ap + st);
    bf16x8 a2 = *(const bf16x8*)(ap + 2 * st);
    bf16x8 a3 = *(const bf16x8*)(ap + 3 * st);
    acc0 = mfma_bf16_16x16x32(a0, bfrag, acc0);
    acc1 = mfma_bf16_16x16x32(a1, bfrag, acc1);
    acc2 = mfma_bf16_16x16x32(a2, bfrag, acc2);
    acc3 = mfma_bf16_16x16x32(a3, bfrag, acc3);
  }
#pragma unroll
  for (int r = 0; r < 4; ++r) {
    const int rr = quad * 4 + r;  // C/D: row = quad*4+reg, col = lane&15
    lds[wave][rr][l15]      = acc0[r];
    lds[wave][16 + rr][l15] = acc1[r];
    lds[wave][32 + rr][l15] = acc2[r];
    lds[wave][48 + rr][l15] = acc3[r];
  }
  __syncthreads();
  const int col = tid & 15, rb = (tid >> 4) << 2;
  const float bvv = bias[bOff + col];
#pragma unroll
  for (int r2 = 0; r2 < 4; ++r2) {
    const int row = rb + r2;
    float v = (lds[0][row][col] + lds[1][row][col] + lds[2][row][col] + lds[3][row][col] + bvv) * scale;
    if (mode == M_SILU)      v = v / (1.f + expf(-v));
    else if (mode == M_SIG)  v = 1.f / (1.f + expf(-v));
    const size_t oi = (size_t)row * outLd + oOff + col;
    if (outF) outF[oi] = v;
    if (outB) outB[oi] = (bf16)v;
  }
}

// ---------------------------------------------------------------------------
// ul+ur fused single-launch GEMM (two independent GEMMs sharing one launch).
// ---------------------------------------------------------------------------
__global__ __launch_bounds__(256) void gemm_ulur(
    const bf16* __restrict__ xn,
    const float* __restrict__ W_ul, const float* __restrict__ W_ur,
    const float* __restrict__ b_ul, const float* __restrict__ b_ur,
    bf16* __restrict__ xl_bf, float* __restrict__ xr_f) {
  __shared__ float lds[4][64][20];
  const int tile = blockIdx.x;
  const int ncol = (tile & 127) * 16;
  if (tile >> 7) {
    gemm_tile<1024>(xn, 1024, 0, W_ur, 2048, ncol, b_ur, ncol, 1.f, M_NONE,
                    xr_f, nullptr, 2048, ncol, lds);
  } else {
    gemm_tile<1024>(xn, 1024, 0, W_ul, 2048, ncol, b_ul, ncol, 1.f, M_NONE,
                    nullptr, xl_bf, 2048, ncol, lds);
  }
}

// ---------------------------------------------------------------------------
// conv_o: conv tap-3 GEMM (8-col tiles -> 256 blocks, full GPU) fused with
// the o-GEMM (A=xl, sigmoid) which only needs xl.  Total grid 384.
//   [0,256):   conv — B cols duplicated across l15&7 (upper halves discarded;
//              duplicate fetches hit the same 16B lines in L1/L2, so HBM
//              traffic is unchanged while active CUs double vs 128-tile grid)
//   [256,384): o tiles (16 cols each)
// ---------------------------------------------------------------------------
__global__ __launch_bounds__(256) void conv_o(
    const bf16* __restrict__ xl, const float* __restrict__ Wc,
    const float* __restrict__ bc,
    const float* __restrict__ W_o, const float* __restrict__ b_o,
    bf16* __restrict__ xc, float* __restrict__ o_f) {
  __shared__ float lds[4][64][20];
  const int bid = blockIdx.x;
  if (bid >= 256) {
    const int ncol = (bid - 256) * 16;
    gemm_tile<2048>(xl, 2048, 0, W_o, 2048, ncol, b_o, ncol, 1.f, M_SIG,
                    o_f, nullptr, 2048, ncol, lds);
    return;
  }
  const int tid = threadIdx.x;
  const int lane = tid & 63, wave = tid >> 6;
  const int l15 = lane & 15, quad = lane >> 4;
  const int n0 = bid * 8;
  const int kbeg = wave * 512;
  f32x4 acc0{}, acc1{}, acc2{}, acc3{};
#pragma unroll 4
  for (int k = 0; k < 512; k += 32) {
    const int kk = kbeg + k + quad * 8;
    bf16x8 bfrag;
    const float* wp = Wc + ((size_t)(n0 + (l15 & 7)) * 2048 + kk) * 4 + 3;
#pragma unroll
    for (int j = 0; j < 8; ++j) bfrag[j] = (bf16)wp[j * 4];
    const bf16* ap = xl + (size_t)l15 * 2048 + kk;
    const size_t st = (size_t)16 * 2048;
    bf16x8 a0 = *(const bf16x8*)(ap);
    bf16x8 a1 = *(const bf16x8*)(ap + st);
    bf16x8 a2 = *(const bf16x8*)(ap + 2 * st);
    bf16x8 a3 = *(const bf16x8*)(ap + 3 * st);
    acc0 = mfma_bf16_16x16x32(a0, bfrag, acc0);
    acc1 = mfma_bf16_16x16x32(a1, bfrag, acc1);
    acc2 = mfma_bf16_16x16x32(a2, bfrag, acc2);
    acc3 = mfma_bf16_16x16x32(a3, bfrag, acc3);
  }
#pragma unroll
  for (int r = 0; r < 4; ++r) {
    const int rr = quad * 4 + r;
    lds[wave][rr][l15]      = acc0[r];
    lds[wave][16 + rr][l15] = acc1[r];
    lds[wave][32 + rr][l15] = acc2[r];
    lds[wave][48 + rr][l15] = acc3[r];
  }
  __syncthreads();
  if (tid < 128) {
    const int col = tid & 7, rb = (tid >> 3) << 2;
    const float bvv = bc[n0 + col];
#pragma unroll
    for (int r2 = 0; r2 < 4; ++r2) {
      const int row = rb + r2;
      float v = lds[0][row][col] + lds[1][row][col] + lds[2][row][col] + lds[3][row][col] + bvv;
      v = v / (1.f + expf(-v));   // silu
      xc[(size_t)row * 2048 + n0 + col] = (bf16)v;
    }
  }
}

// ---------------------------------------------------------------------------
// mega_c: everything that depends on xc, one launch (o moved to conv_o).
//   blocks [0,128):   skip (A=xc)
//   blocks [128,512): block-diagonal q/k/v GEMMs (K=256 per head)
//   blocks [512,576): i_t/f_t GEMV + stabilized gates + m_t
// ---------------------------------------------------------------------------
__global__ __launch_bounds__(256) void mega_c(
    const bf16* __restrict__ xc, const bf16* __restrict__ xl,
    const float* __restrict__ W_skip, const float* __restrict__ b_skip,
    const float* __restrict__ Wq, const float* __restrict__ bq,
    const float* __restrict__ Wk, const float* __restrict__ bk,
    const float* __restrict__ Wv, const float* __restrict__ bv,
    const float* __restrict__ Wi, const float* __restrict__ bi,
    const float* __restrict__ Wf, const float* __restrict__ bfv,
    const float* __restrict__ m_prev,
    float* __restrict__ xskip_f,
    float* __restrict__ qf, float* __restrict__ kf, float* __restrict__ vf,
    float* __restrict__ ig, float* __restrict__ fgo, float* __restrict__ mt_out) {
  __shared__ float lds[4][64][20];  // 20 KB; gates branch reuses first 16 KB
  const int bid = blockIdx.x;
  if (bid < 128) {
    const int ncol = bid * 16;
    gemm_tile<2048>(xc, 2048, 0, W_skip, 2048, ncol, b_skip, ncol, 1.f, M_NONE,
                    xskip_f, nullptr, 2048, ncol, lds);
  } else if (bid < 512) {
    const int t6 = bid - 128;
    const int seg = t6 >> 7, t = t6 & 127;
    const int n0 = t * 16, h = t >> 4;
    const bf16* A = (seg == 2) ? xl : xc;
    const float* W = (seg == 0) ? Wq : (seg == 1) ? Wk : Wv;
    const float* bias = (seg == 0) ? bq : (seg == 1) ? bk : bv;
    float* out = (seg == 0) ? qf : (seg == 1) ? kf : vf;
    gemm_tile<256>(A, 2048, h << 8, W + (size_t)h * 65536, 256, n0 & 255,
                   bias, n0, (seg == 1) ? 0.0625f : 1.f, M_NONE,
                   out, nullptr, 2048, n0, lds);
  } else {
    // gates: i_t/f_t GEMV over xc, stabilized exponential gating
    const int b = bid - 512, tid = threadIdx.x;
    float* shf = &lds[0][0][0];
    float (*ri)[8] = reinterpret_cast<float(*)[8]>(shf);          // 256*8
    float (*rf)[8] = reinterpret_cast<float(*)[8]>(shf + 2048);   // 256*8
    float ai[8] = {}, af[8] = {};
    for (int k = tid; k < 2048; k += 256) {
      const float xv = (float)xc[b * 2048 + k];
      const float4 wi0 = *(const float4*)(Wi + (size_t)k * 8);
      const float4 wi1 = *(const float4*)(Wi + (size_t)k * 8 + 4);
      const float4 wf0 = *(const float4*)(Wf + (size_t)k * 8);
      const float4 wf1 = *(const float4*)(Wf + (size_t)k * 8 + 4);
      ai[0] += xv * wi0.x; ai[1] += xv * wi0.y; ai[2] += xv * wi0.z; ai[3] += xv * wi0.w;
      ai[4] += xv * wi1.x; ai[5] += xv * wi1.y; ai[6] += xv * wi1.z; ai[7] += xv * wi1.w;
      af[0] += xv * wf0.x; af[1] += xv * wf0.y; af[2] += xv * wf0.z; af[3] += xv * wf0.w;
      af[4] += xv * wf1.x; af[5] += xv * wf1.y; af[6] += xv * wf1.z; af[7] += xv * wf1.w;
    }
#pragma unroll
    for (int h = 0; h < 8; ++h) { ri[tid][h] = ai[h]; rf[tid][h] = af[h]; }
    __syncthreads();
    for (int off = 128; off; off >>= 1) {
      if (tid < off) {
#pragma unroll
        for (int h = 0; h < 8; ++h) { ri[tid][h] += ri[tid + off][h]; rf[tid][h] += rf[tid + off][h]; }
      }
      __syncthreads();
    }
    if (tid < 8) {
      const float it = ri[0][tid] + bi[tid];
      const float ft = rf[0][tid] + bfv[tid];
      const float mp = m_prev[b * 8 + tid];
      const float mt = fmaxf(ft + mp, it);
      mt_out[b * 8 + tid] = mt;
      ig[b * 8 + tid] = expf(it - mt);
      fgo[b * 8 + tid] = expf(ft + mp - mt);
    }
  }
}

// ---------------------------------------------------------------------------
// state_fused: one block per (b,h).
//   phase 1: c_t = f*c_prev + i*v⊗k, num[row] = c_t[row]·q   (num kept in LDS)
//   phase 2: n_t, den, h_t, GroupNorm, pre = (gn*w+b + skip)*silu(xr)
// c_prev/c_t use nontemporal access (134 MB pure stream; keep L2 for weights).
// ---------------------------------------------------------------------------
__global__ __launch_bounds__(256) void state_fused(
    const float* __restrict__ c_prev, const float* __restrict__ n_prev,
    const float* __restrict__ qf, const float* __restrict__ kf,
    const float* __restrict__ vf, const float* __restrict__ of,
    const float* __restrict__ ig, const float* __restrict__ fg,
    const float* __restrict__ xskip, const float* __restrict__ xrf,
    const float* __restrict__ gnw, const float* __restrict__ gnb,
    float* __restrict__ ct_out, float* __restrict__ nt_out,
    float* __restrict__ ht_out, bf16* __restrict__ pre_bf) {
  const int bh = blockIdx.x, b = bh >> 3, h = bh & 7;
  const int tid = threadIdx.x;
  const int vb = b * 2048 + h * 256;
  __shared__ float q_s[256], k_s[256], num_s[256], red[256];
  q_s[tid] = qf[vb + tid];
  k_s[tid] = kf[vb + tid];
  const float i_g = ig[bh], f_g = fg[bh];
  __syncthreads();
  const int lane8 = tid & 7, rowbase = tid >> 3;
#pragma unroll
  for (int rg = 0; rg < 8; ++rg) {
    const int row = rg * 32 + rowbase;
    const float iv = i_g * vf[vb + row];
    const size_t base = ((size_t)bh << 16) + ((size_t)row << 8) + lane8 * 4;
    float p = 0.f;
#pragma unroll
    for (int i = 0; i < 8; ++i) {
      const int c = lane8 * 4 + i * 32;
      const float4 cp = nt_load4(c_prev + base + i * 32);
      float4 cn;
      cn.x = f_g * cp.x + iv * k_s[c];
      cn.y = f_g * cp.y + iv * k_s[c + 1];
      cn.z = f_g * cp.z + iv * k_s[c + 2];
      cn.w = f_g * cp.w + iv * k_s[c + 3];
      nt_store4(ct_out + base + i * 32, cn);
      p += cn.x * q_s[c] + cn.y * q_s[c + 1] + cn.z * q_s[c + 2] + cn.w * q_s[c + 3];
    }
    p += __shfl_xor(p, 1, 64);
    p += __shfl_xor(p, 2, 64);
    p += __shfl_xor(p, 4, 64);
    if (lane8 == 0) num_s[row] = p;
  }
  __syncthreads();
  // phase 2, q/k from LDS, num from LDS
  const float qv = q_s[tid], kv = k_s[tid];
  const float nv = f_g * n_prev[bh * 256 + tid] + i_g * kv;
  nt_out[bh * 256 + tid] = nv;
  red[tid] = nv * qv;
  __syncthreads();
  for (int off = 128; off; off >>= 1) { if (tid < off) red[tid] += red[tid + off]; __syncthreads(); }
  const float den = fmaxf(red[0], 1.0f);
  const float hv = of[vb + tid] * num_s[tid] / den;
  ht_out[bh * 256 + tid] = hv;
  __syncthreads();
  red[tid] = hv; __syncthreads();
  for (int off = 128; off; off >>= 1) { if (tid < off) red[tid] += red[tid + off]; __syncthreads(); }
  const float mu = red[0] * (1.f / 256.f);
  __syncthreads();
  const float dv = hv - mu;
  red[tid] = dv * dv; __syncthreads();
  for (int off = 128; off; off >>= 1) { if (tid < off) red[tid] += red[tid + off]; __syncthreads(); }
  const float gn = (hv - mu) * rsqrtf(red[0] * (1.f / 256.f) + 1e-5f);
  const int j = h * 256 + tid;
  const float xr = xrf[b * 2048 + j];
  const float pre = (gn * gnw[j] + gnb[j] + xskip[b * 2048 + j]) * (xr / (1.f + expf(-xr)));
  pre_bf[b * 2048 + j] = (bf16)pre;
}

// ---------------------------------------------------------------------------
// Split-K atomic GEMM for W_down (base out_final = x + b_down from ln_kernel).
// ---------------------------------------------------------------------------
template <int K, int KS, int NTILES>
__global__ __launch_bounds__(256) void gemm_atomic(
    const bf16* __restrict__ A, const float* __restrict__ W,
    int ldA, int ldB, float* __restrict__ dst, int outN) {
  constexpr int Kslice = K / KS;
  constexpr int chunk = Kslice / 4;
  const int tid = threadIdx.x;
  const int lane = tid & 63, wave = tid >> 6;
  const int l15 = lane & 15, quad = lane >> 4;
  const int tile = blockIdx.x % NTILES, ks = blockIdx.x / NTILES;
  const int ncol = tile * 16;
  const int kbeg = ks * Kslice + wave * chunk;

  f32x4 acc0{}, acc1{}, acc2{}, acc3{};
#pragma unroll
  for (int k = 0; k < chunk; k += 32) {
    const int kk = kbeg + k + quad * 8;
    bf16x8 bfrag;
    const float* wp = W + (size_t)kk * ldB + ncol + l15;
#pragma unroll
    for (int j = 0; j < 8; ++j) bfrag[j] = (bf16)wp[(size_t)j * ldB];
    const bf16* ap = A + (size_t)l15 * ldA + kk;
    const size_t st = (size_t)16 * ldA;
    bf16x8 a0 = *(const bf16x8*)(ap);
    bf16x8 a1 = *(const bf16x8*)(ap + st);
    bf16x8 a2 = *(const bf16x8*)(ap + 2 * st);
    bf16x8 a3 = *(const bf16x8*)(ap + 3 * st);
    acc0 = mfma_bf16_16x16x32(a0, bfrag, acc0);
    acc1 = mfma_bf16_16x16x32(a1, bfrag, acc1);
    acc2 = mfma_bf16_16x16x32(a2, bfrag, acc2);
    acc3 = mfma_bf16_16x16x32(a3, bfrag, acc3);
  }
  __shared__ float lds[4][64][20];
#pragma unroll
  for (int r = 0; r < 4; ++r) {
    const int rr = quad * 4 + r;
    lds[wave][rr][l15]      = acc0[r];
    lds[wave][16 + rr][l15] = acc1[r];
    lds[wave][32 + rr][l15] = acc2[r];
    lds[wave][48 + rr][l15] = acc3[r];
  }
  __syncthreads();
  const int col = tid & 15, rb = (tid >> 4) << 2;
#pragma unroll
  for (int r2 = 0; r2 < 4; ++r2) {
    const int row = rb + r2;
    const float v = lds[0][row][col] + lds[1][row][col] + lds[2][row][col] + lds[3][row][col];
    atomicAdd(dst + (size_t)row * outN + ncol + col, v);
  }
}

// ---------------------------------------------------------------------------
extern "C" void kernel_launch(void* const* d_in, const int* in_sizes, int n_in,
                              void* d_out, int out_size, void* d_ws, size_t ws_size,
                              hipStream_t stream) {
  (void)in_sizes; (void)n_in; (void)out_size; (void)ws_size;
  const float* x      = (const float*)d_in[0];
  const float* c_prev = (const float*)d_in[2];
  const float* n_prev = (const float*)d_in[3];
  const float* m_prev = (const float*)d_in[4];
  const float* ln_w = (const float*)d_in[5];
  const float* ln_b = (const float*)d_in[6];
  const float* W_ul = (const float*)d_in[7];
  const float* b_ul = (const float*)d_in[8];
  const float* W_ur = (const float*)d_in[9];
  const float* b_ur = (const float*)d_in[10];
  const float* W_conv = (const float*)d_in[11];
  const float* b_conv = (const float*)d_in[12];
  const float* W_skip = (const float*)d_in[13];
  const float* b_skip = (const float*)d_in[14];
  const float* W_q = (const float*)d_in[15];
  const float* b_q = (const float*)d_in[16];
  const float* W_k = (const float*)d_in[17];
  const float* b_k = (const float*)d_in[18];
  const float* W_v = (const float*)d_in[19];
  const float* b_v = (const float*)d_in[20];
  const float* W_i = (const float*)d_in[21];
  const float* b_i = (const float*)d_in[22];
  const float* W_f = (const float*)d_in[23];
  const float* b_f = (const float*)d_in[24];
  const float* W_o = (const float*)d_in[25];
  const float* b_o = (const float*)d_in[26];
  const float* W_down = (const float*)d_in[27];
  const float* b_down = (const float*)d_in[28];
  const float* gn_w = (const float*)d_in[29];
  const float* gn_b = (const float*)d_in[30];

  // d_out layout (f32 elements): final | h_t | c_t | n_t | m_t
  float* out_final = (float*)d_out;
  float* out_ht = out_final + 65536;
  float* out_ct = out_final + 196608;
  float* out_nt = out_final + 33751040;
  float* out_mt = out_final + 33882112;

  char* ws = (char*)d_ws;
  bf16*  xn_bf   = (bf16*)(ws + 0);         // 128 KB
  bf16*  xl_bf   = (bf16*)(ws + 131072);    // 256 KB
  bf16*  xc_bf   = (bf16*)(ws + 393216);    // 256 KB
  bf16*  pre_bf  = (bf16*)(ws + 655360);    // 256 KB
  float* xr_f    = (float*)(ws + 917504);   // 512 KB
  float* xskip_f = (float*)(ws + 1441792);  // 512 KB
  float* q_f     = (float*)(ws + 1966080);
  float* k_f     = (float*)(ws + 2490368);
  float* v_f     = (float*)(ws + 3014656);
  float* o_f     = (float*)(ws + 3538944);
  float* ig_f    = (float*)(ws + 4063232);  // 2 KB
  float* fg_f    = (float*)(ws + 4065280);  // 2 KB

  // 1. LayerNorm + final-residual base
  ln_kernel<<<64, 256, 0, stream>>>(x, ln_w, ln_b, b_down, xn_bf, out_final);
  // 2. ul+ur fused single-launch GEMM (K=1024, N=2048+2048)
  gemm_ulur<<<256, 256, 0, stream>>>(xn_bf, W_ul, W_ur, b_ul, b_ur, xl_bf, xr_f);
  // 3. conv (256 x 8-col tiles, full GPU) + o-GEMM (needs only xl), one launch
  conv_o<<<384, 256, 0, stream>>>(xl_bf, W_conv, b_conv, W_o, b_o, xc_bf, o_f);
  // 4. skip + q/k/v + gates, one launch
  mega_c<<<576, 256, 0, stream>>>(
      xc_bf, xl_bf, W_skip, b_skip, W_q, b_q, W_k, b_k, W_v, b_v,
      W_i, b_i, W_f, b_f, m_prev, xskip_f, q_f, k_f, v_f, ig_f, fg_f, out_mt);
  // 5. fused state update + readout + GroupNorm + pre-down activation
  state_fused<<<512, 256, 0, stream>>>(
      c_prev, n_prev, q_f, k_f, v_f, o_f, ig_f, fg_f,
      xskip_f, xr_f, gn_w, gn_b, out_ct, out_nt, out_ht, pre_bf);
  // 6. W_down: split-K atomic into out_final (base = x + b_down)
  gemm_atomic<2048, 8, 64><<<512, 256, 0, stream>>>(
      pre_bf, W_down, 2048, 1024, out_final, 1024);
}